// Round 1
// baseline (2673.199 us; speedup 1.0000x reference)
//
#include <hip/hip_runtime.h>
#include <math.h>

#define NNODES 65536
#define NEDGES 1048576
#define NF 32
#define EF 16
#define HD 128
#define NACT 10
#define NB 64
#define NPER 1024

__device__ __forceinline__ float leakyf(float v) { return v > 0.0f ? v : 0.01f * v; }

// ---------------- edge layer 1: msg = relu(x[src] + ea@e1_w + e1_b), atomic agg ----------------
// 8 threads per edge (4 features each), 32 edges per block pass.
__global__ __launch_bounds__(256) void e1_kernel(
    const float* __restrict__ x, const int* __restrict__ ei,
    const float* __restrict__ ea, const float* __restrict__ w,
    const float* __restrict__ b, float* __restrict__ agg)
{
    __shared__ __align__(16) float sw[EF * NF];   // 2 KB
    __shared__ float sea[32][EF + 1];             // pad to break bank aliasing
    const int tid = threadIdx.x;
    const int q  = tid & 7;    // feature quad
    const int el = tid >> 3;   // edge within tile
    for (int i = tid; i < EF * NF; i += 256) sw[i] = w[i];
    const float4 bias = ((const float4*)b)[q];
    const int ntiles = NEDGES / 32;
    for (int tile = blockIdx.x; tile < ntiles; tile += gridDim.x) {
        const int ebase = tile * 32;
        __syncthreads();
        for (int i = tid; i < 32 * EF; i += 256)
            sea[i >> 4][i & 15] = ea[(size_t)ebase * EF + i];
        __syncthreads();
        const int e   = ebase + el;
        const int src = ei[e];
        const int dst = ei[NEDGES + e];
        float4 acc = bias;
        #pragma unroll
        for (int k = 0; k < EF; ++k) {
            const float a = sea[el][k];
            const float4 wv = ((const float4*)sw)[k * 8 + q];
            acc.x = fmaf(a, wv.x, acc.x);
            acc.y = fmaf(a, wv.y, acc.y);
            acc.z = fmaf(a, wv.z, acc.z);
            acc.w = fmaf(a, wv.w, acc.w);
        }
        const float4 xv = ((const float4*)x)[src * 8 + q];
        float* ap = &agg[(size_t)dst * NF + q * 4];
        atomicAdd(ap + 0, fmaxf(xv.x + acc.x, 0.0f));
        atomicAdd(ap + 1, fmaxf(xv.y + acc.y, 0.0f));
        atomicAdd(ap + 2, fmaxf(xv.z + acc.z, 0.0f));
        atomicAdd(ap + 3, fmaxf(xv.w + acc.w, 0.0f));
    }
}

// ---------------- edge layer 2: msg = relu(h[src] + ea@e2_w + e2_b), atomic agg ----------------
// 32 threads per edge (4 features each), 8 edges per block pass.
__global__ __launch_bounds__(256) void e2_kernel(
    const float* __restrict__ h, const int* __restrict__ ei,
    const float* __restrict__ ea, const float* __restrict__ w,
    const float* __restrict__ b, float* __restrict__ agg)
{
    __shared__ __align__(16) float sw[EF * HD];   // 8 KB
    __shared__ float sea[8][EF + 1];
    const int tid = threadIdx.x;
    const int q  = tid & 31;   // feature quad 0..31
    const int el = tid >> 5;   // edge within tile 0..7
    for (int i = tid; i < EF * HD; i += 256) sw[i] = w[i];
    const float4 bias = ((const float4*)b)[q];
    const int ntiles = NEDGES / 8;
    for (int tile = blockIdx.x; tile < ntiles; tile += gridDim.x) {
        const int ebase = tile * 8;
        __syncthreads();
        if (tid < 8 * EF) sea[tid >> 4][tid & 15] = ea[(size_t)ebase * EF + tid];
        __syncthreads();
        const int e   = ebase + el;
        const int src = ei[e];
        const int dst = ei[NEDGES + e];
        float4 acc = bias;
        #pragma unroll
        for (int k = 0; k < EF; ++k) {
            const float a = sea[el][k];
            const float4 wv = ((const float4*)sw)[k * 32 + q];
            acc.x = fmaf(a, wv.x, acc.x);
            acc.y = fmaf(a, wv.y, acc.y);
            acc.z = fmaf(a, wv.z, acc.z);
            acc.w = fmaf(a, wv.w, acc.w);
        }
        const float4 hv = ((const float4*)h)[(size_t)src * 32 + q];
        float* ap = &agg[(size_t)dst * HD + q * 4];
        atomicAdd(ap + 0, fmaxf(hv.x + acc.x, 0.0f));
        atomicAdd(ap + 1, fmaxf(hv.y + acc.y, 0.0f));
        atomicAdd(ap + 2, fmaxf(hv.z + acc.z, 0.0f));
        atomicAdd(ap + 3, fmaxf(hv.w + acc.w, 0.0f));
    }
}

// 8-node-batched matvec: thread tid owns output feature tid; inputs broadcast from LDS.
__device__ __forceinline__ void mv8(const float* __restrict__ sIn, int ld, int K,
                                    const float* __restrict__ w, float bias,
                                    int tid, float* __restrict__ acc)
{
    #pragma unroll
    for (int n = 0; n < 8; ++n) acc[n] = bias;
    for (int k = 0; k < K; k += 4) {
        const float w0 = w[(k + 0) * HD + tid];
        const float w1 = w[(k + 1) * HD + tid];
        const float w2 = w[(k + 2) * HD + tid];
        const float w3 = w[(k + 3) * HD + tid];
        #pragma unroll
        for (int n = 0; n < 8; ++n) {
            const float4 iv = *(const float4*)&sIn[n * ld + k];
            acc[n] = fmaf(iv.w, w3, fmaf(iv.z, w2, fmaf(iv.y, w1, fmaf(iv.x, w0, acc[n]))));
        }
    }
}

// ---------------- node MLP layer 1 (fused): h = relu(leaky((x+agg1)@w1+b1)@w2+b2) ----------------
__global__ __launch_bounds__(128) void n1_kernel(
    const float* __restrict__ x, const float* __restrict__ agg,
    const float* __restrict__ w1, const float* __restrict__ b1,
    const float* __restrict__ w2, const float* __restrict__ b2,
    float* __restrict__ hout)
{
    __shared__ __align__(16) float inA[8][NF];
    __shared__ __align__(16) float bufB[8][HD];
    const int tid = threadIdx.x;
    const float bias1 = b1[tid];
    const float bias2 = b2[tid];
    const int ntiles = NNODES / 8;
    for (int tile = blockIdx.x; tile < ntiles; tile += gridDim.x) {
        const size_t base = (size_t)tile * 8 * NF;
        __syncthreads();
        #pragma unroll
        for (int i = tid; i < 8 * NF; i += 128)
            inA[i >> 5][i & 31] = x[base + i] + agg[base + i];
        __syncthreads();
        float acc[8];
        mv8(&inA[0][0], NF, NF, w1, bias1, tid, acc);
        #pragma unroll
        for (int n = 0; n < 8; ++n) bufB[n][tid] = leakyf(acc[n]);
        __syncthreads();
        mv8(&bufB[0][0], HD, HD, w2, bias2, tid, acc);
        const size_t ob = (size_t)tile * 8 * HD;
        #pragma unroll
        for (int n = 0; n < 8; ++n)
            hout[ob + n * HD + tid] = fmaxf(acc[n], 0.0f);   // relu(leaky(z)) == relu(z)
    }
}

// ---- node layer 2 + pooling + node-score head, all fused (h2 never leaves the CU) ----
__global__ __launch_bounds__(128) void n2_kernel(
    const float* __restrict__ h, const float* __restrict__ agg,
    const float* __restrict__ w1, const float* __restrict__ b1,
    const float* __restrict__ w2, const float* __restrict__ b2,
    const float* __restrict__ nw1, const float* __restrict__ nb1,
    const float* __restrict__ nw2, const float* __restrict__ nb2,
    const float* __restrict__ nw3, const float* __restrict__ nb3,
    float* __restrict__ pooled, float* __restrict__ scores)
{
    __shared__ __align__(16) float bufA[8][HD];
    __shared__ __align__(16) float bufB[8][HD];
    __shared__ float red[2][8];
    const int tid = threadIdx.x;
    const float bias1  = b1[tid],  bias2  = b2[tid];
    const float nbias1 = nb1[tid], nbias2 = nb2[tid];
    const float w3v = nw3[tid];
    const float b3v = nb3[0];
    const int ntiles = NNODES / 8;
    for (int tile = blockIdx.x; tile < ntiles; tile += gridDim.x) {
        const size_t base = (size_t)tile * 8 * HD;
        __syncthreads();                                       // S0
        for (int i = tid; i < 8 * HD; i += 128)
            bufA[i >> 7][i & 127] = h[base + i] + agg[base + i];
        __syncthreads();                                       // S1
        float acc[8];
        mv8(&bufA[0][0], HD, HD, w1, bias1, tid, acc);
        #pragma unroll
        for (int n = 0; n < 8; ++n) bufB[n][tid] = leakyf(acc[n]);
        __syncthreads();                                       // S2
        mv8(&bufB[0][0], HD, HD, w2, bias2, tid, acc);
        float h2[8];
        float psum = 0.0f;
        #pragma unroll
        for (int n = 0; n < 8; ++n) { h2[n] = leakyf(acc[n]); psum += h2[n]; }
        atomicAdd(&pooled[(tile >> 7) * HD + tid], psum);      // graph = (tile*8)/1024
        #pragma unroll
        for (int n = 0; n < 8; ++n) bufA[n][tid] = h2[n];      // bufA reads all done before S2
        __syncthreads();                                       // S3
        mv8(&bufA[0][0], HD, HD, nw1, nbias1, tid, acc);
        #pragma unroll
        for (int n = 0; n < 8; ++n) bufB[n][tid] = leakyf(acc[n]);
        __syncthreads();                                       // S4
        mv8(&bufB[0][0], HD, HD, nw2, nbias2, tid, acc);
        float v[8];
        #pragma unroll
        for (int n = 0; n < 8; ++n) v[n] = leakyf(acc[n]) * w3v;
        #pragma unroll
        for (int off = 32; off >= 1; off >>= 1) {
            #pragma unroll
            for (int n = 0; n < 8; ++n) v[n] += __shfl_xor(v[n], off, 64);
        }
        if ((tid & 63) == 0) {
            const int wv = tid >> 6;
            #pragma unroll
            for (int n = 0; n < 8; ++n) red[wv][n] = v[n];
        }
        __syncthreads();                                       // S5
        if (tid < 8) {
            const int node = tile * 8 + tid;
            const float s = red[0][tid] + red[1][tid] + b3v;
            const float sc = 1.0f / (1.0f + expf(-s));
            scores[(node & 63) * NPER + (node >> 6)] = sc;     // [B, Nper] transpose
        }
    }
}

// ---------------- action head: pooled mean -> MLP -> softmax ----------------
__global__ __launch_bounds__(128) void act_kernel(
    const float* __restrict__ pooled,
    const float* __restrict__ w1, const float* __restrict__ b1,
    const float* __restrict__ w2, const float* __restrict__ b2,
    float* __restrict__ out)
{
    __shared__ __align__(16) float p[HD];
    __shared__ float a1[HD];
    __shared__ float z[NACT];
    __shared__ float red2[2];
    const int g = blockIdx.x;
    const int tid = threadIdx.x;
    p[tid] = pooled[g * HD + tid] * (1.0f / NPER);
    __syncthreads();
    float acc = b1[tid];
    for (int k = 0; k < HD; ++k) acc = fmaf(p[k], w1[k * HD + tid], acc);
    a1[tid] = leakyf(acc);
    __syncthreads();
    if (tid < NACT) {
        float a2 = b2[tid];
        for (int k = 0; k < HD; ++k) a2 = fmaf(a1[k], w2[k * NACT + tid], a2);
        z[tid] = leakyf(a2);
    }
    __syncthreads();
    if (tid == 0) {
        float m = z[0];
        for (int i = 1; i < NACT; ++i) m = fmaxf(m, z[i]);
        red2[0] = m;
    }
    __syncthreads();
    if (tid < NACT) z[tid] = expf(z[tid] - red2[0]);
    __syncthreads();
    if (tid == 0) {
        float s = 0.0f;
        for (int i = 0; i < NACT; ++i) s += z[i];
        red2[1] = s;
    }
    __syncthreads();
    if (tid < NACT) out[g * NACT + tid] = z[tid] / red2[1];
}

extern "C" void kernel_launch(void* const* d_in, const int* in_sizes, int n_in,
                              void* d_out, int out_size, void* d_ws, size_t ws_size,
                              hipStream_t stream)
{
    const float* x    = (const float*)d_in[0];
    const int*   ei   = (const int*)d_in[1];     // int32 (jax x64 disabled)
    const float* ea   = (const float*)d_in[2];
    const float* e1w  = (const float*)d_in[3];
    const float* e1b  = (const float*)d_in[4];
    const float* c1w1 = (const float*)d_in[5];
    const float* c1b1 = (const float*)d_in[6];
    const float* c1w2 = (const float*)d_in[7];
    const float* c1b2 = (const float*)d_in[8];
    const float* e2w  = (const float*)d_in[9];
    const float* e2b  = (const float*)d_in[10];
    const float* c2w1 = (const float*)d_in[11];
    const float* c2b1 = (const float*)d_in[12];
    const float* c2w2 = (const float*)d_in[13];
    const float* c2b2 = (const float*)d_in[14];
    const float* aw1  = (const float*)d_in[15];
    const float* ab1  = (const float*)d_in[16];
    const float* aw2  = (const float*)d_in[17];
    const float* ab2  = (const float*)d_in[18];
    const float* nw1  = (const float*)d_in[19];
    const float* nb1  = (const float*)d_in[20];
    const float* nw2  = (const float*)d_in[21];
    const float* nb2  = (const float*)d_in[22];
    const float* nw3  = (const float*)d_in[23];
    const float* nb3  = (const float*)d_in[24];

    float* out = (float*)d_out;
    char*  ws  = (char*)d_ws;
    // workspace layout: agg1 8MB | h 32MB | agg2 32MB | pooled 32KB  (~72 MB total)
    float* agg1   = (float*)(ws);
    float* h      = (float*)(ws + (size_t)8  * 1024 * 1024);
    float* agg2   = (float*)(ws + (size_t)40 * 1024 * 1024);
    float* pooled = (float*)(ws + (size_t)72 * 1024 * 1024);

    hipMemsetAsync(agg1,   0, (size_t)NNODES * NF * sizeof(float), stream);
    hipMemsetAsync(agg2,   0, (size_t)NNODES * HD * sizeof(float), stream);
    hipMemsetAsync(pooled, 0, (size_t)NB * HD * sizeof(float), stream);

    e1_kernel<<<4096, 256, 0, stream>>>(x, ei, ea, e1w, e1b, agg1);
    n1_kernel<<<8192, 128, 0, stream>>>(x, agg1, c1w1, c1b1, c1w2, c1b2, h);
    e2_kernel<<<8192, 256, 0, stream>>>(h, ei, ea, e2w, e2b, agg2);
    n2_kernel<<<8192, 128, 0, stream>>>(h, agg2, c2w1, c2b1, c2w2, c2b2,
                                        nw1, nb1, nw2, nb2, nw3, nb3,
                                        pooled, out + NB * NACT);
    act_kernel<<<NB, 128, 0, stream>>>(pooled, aw1, ab1, aw2, ab2, out);
}

// Round 2
// 988.080 us; speedup vs baseline: 2.7054x; 2.7054x over previous
//
#include <hip/hip_runtime.h>
#include <math.h>

#define NNODES 65536
#define NEDGES 1048576
#define NF 32
#define EF 16
#define HD 128
#define NACT 10
#define NB 64
#define NPER 1024

__device__ __forceinline__ float leakyf(float v) { return v > 0.0f ? v : 0.01f * v; }

__device__ __forceinline__ void load_ea16(const float* __restrict__ ea, int eidx, float* ev)
{
    const float4* p = (const float4*)ea + (size_t)eidx * 4;
    const float4 a0 = p[0], a1 = p[1], a2 = p[2], a3 = p[3];
    ev[0]=a0.x; ev[1]=a0.y; ev[2]=a0.z; ev[3]=a0.w;
    ev[4]=a1.x; ev[5]=a1.y; ev[6]=a1.z; ev[7]=a1.w;
    ev[8]=a2.x; ev[9]=a2.y; ev[10]=a2.z; ev[11]=a2.w;
    ev[12]=a3.x; ev[13]=a3.y; ev[14]=a3.z; ev[15]=a3.w;
}

// ---------------- CSR build: histogram -> scan -> scatter ----------------
__global__ __launch_bounds__(256) void hist_kernel(const int* __restrict__ ei, int* __restrict__ cnt)
{
    const int i = blockIdx.x * 256 + threadIdx.x;
    if (i < NEDGES) atomicAdd(&cnt[ei[NEDGES + i]], 1);
}

__global__ __launch_bounds__(1024) void scan_kernel(const int* __restrict__ cnt, int* __restrict__ rs)
{
    __shared__ int s[1024];
    const int t = threadIdx.x;
    int loc[64];
    int tot = 0;
    const int4* c4 = (const int4*)(cnt + t * 64);
    #pragma unroll
    for (int j = 0; j < 16; ++j) {
        const int4 v = c4[j];
        loc[4*j+0] = v.x; loc[4*j+1] = v.y; loc[4*j+2] = v.z; loc[4*j+3] = v.w;
        tot += v.x + v.y + v.z + v.w;
    }
    s[t] = tot;
    __syncthreads();
    for (int off = 1; off < 1024; off <<= 1) {
        const int v = (t >= off) ? s[t - off] : 0;
        __syncthreads();
        s[t] += v;
        __syncthreads();
    }
    int run = s[t] - tot;   // exclusive prefix
    #pragma unroll
    for (int j = 0; j < 64; ++j) { rs[t * 64 + j] = run; run += loc[j]; }
    if (t == 0) rs[NNODES] = NEDGES;
}

__global__ __launch_bounds__(256) void scatter_kernel(
    const int* __restrict__ ei, const int* __restrict__ rs, int* __restrict__ fill,
    int* __restrict__ ssrc, int* __restrict__ seidx)
{
    const int i = blockIdx.x * 256 + threadIdx.x;
    if (i < NEDGES) {
        const int d = ei[NEDGES + i];
        const int pos = rs[d] + atomicAdd(&fill[d], 1);
        ssrc[pos]  = ei[i];
        seidx[pos] = i;
    }
}

// ---------------- edge layer 1 (gather): agg1[n] = sum relu(x[src] + ea@W + b) ----------------
// One wave per node; lane = (half, feature): f = lane&31, halves split the edge list.
__global__ __launch_bounds__(256) void e1_agg_kernel(
    const float* __restrict__ x, const int* __restrict__ rs,
    const int* __restrict__ ssrc, const int* __restrict__ seidx,
    const float* __restrict__ ea, const float* __restrict__ w,
    const float* __restrict__ b, float* __restrict__ agg)
{
    const int tid  = threadIdx.x;
    const int lane = tid & 63;
    const int f    = lane & 31;
    const int half = lane >> 5;
    const int node = blockIdx.x * 4 + (tid >> 6);
    float wr[EF];
    #pragma unroll
    for (int k = 0; k < EF; ++k) wr[k] = w[k * NF + f];
    const float bf = b[f];
    const int beg = rs[node], end = rs[node + 1];
    float acc = 0.0f;
    for (int e = beg + half; e < end; e += 2) {
        const int src  = ssrc[e];
        const int eidx = seidx[e];
        float ev[EF];
        load_ea16(ea, eidx, ev);
        float m = bf;
        #pragma unroll
        for (int k = 0; k < EF; ++k) m = fmaf(ev[k], wr[k], m);
        acc += fmaxf(x[(size_t)src * NF + f] + m, 0.0f);
    }
    acc += __shfl_xor(acc, 32, 64);
    if (half == 0) agg[(size_t)node * NF + f] = acc;
}

// ---------------- edge layer 2 (gather): agg2[n] = sum relu(h[src] + ea@W + b) ----------------
// One wave per node; lane owns features lane and lane+64. Weights hoisted to registers.
__global__ __launch_bounds__(256) void e2_agg_kernel(
    const float* __restrict__ h, const int* __restrict__ rs,
    const int* __restrict__ ssrc, const int* __restrict__ seidx,
    const float* __restrict__ ea, const float* __restrict__ w,
    const float* __restrict__ b, float* __restrict__ agg)
{
    const int tid  = threadIdx.x;
    const int lane = tid & 63;
    const int node = blockIdx.x * 4 + (tid >> 6);
    float wr0[EF], wr1[EF];
    #pragma unroll
    for (int k = 0; k < EF; ++k) {
        wr0[k] = w[k * HD + lane];
        wr1[k] = w[k * HD + lane + 64];
    }
    const float b0 = b[lane], b1 = b[lane + 64];
    const int beg = rs[node], end = rs[node + 1];
    float acc0 = 0.0f, acc1 = 0.0f;
    for (int e = beg; e < end; ++e) {
        const int src  = ssrc[e];
        const int eidx = seidx[e];
        float ev[EF];
        load_ea16(ea, eidx, ev);
        float m0 = b0, m1 = b1;
        #pragma unroll
        for (int k = 0; k < EF; ++k) {
            m0 = fmaf(ev[k], wr0[k], m0);
            m1 = fmaf(ev[k], wr1[k], m1);
        }
        const float hv0 = h[(size_t)src * HD + lane];
        const float hv1 = h[(size_t)src * HD + lane + 64];
        acc0 += fmaxf(hv0 + m0, 0.0f);
        acc1 += fmaxf(hv1 + m1, 0.0f);
    }
    agg[(size_t)node * HD + lane]      = acc0;
    agg[(size_t)node * HD + lane + 64] = acc1;
}

// 8-node-batched matvec: thread tid owns output feature tid; inputs broadcast from LDS.
__device__ __forceinline__ void mv8(const float* __restrict__ sIn, int ld, int K,
                                    const float* __restrict__ w, float bias,
                                    int tid, float* __restrict__ acc)
{
    #pragma unroll
    for (int n = 0; n < 8; ++n) acc[n] = bias;
    for (int k = 0; k < K; k += 4) {
        const float w0 = w[(k + 0) * HD + tid];
        const float w1 = w[(k + 1) * HD + tid];
        const float w2 = w[(k + 2) * HD + tid];
        const float w3 = w[(k + 3) * HD + tid];
        #pragma unroll
        for (int n = 0; n < 8; ++n) {
            const float4 iv = *(const float4*)&sIn[n * ld + k];
            acc[n] = fmaf(iv.w, w3, fmaf(iv.z, w2, fmaf(iv.y, w1, fmaf(iv.x, w0, acc[n]))));
        }
    }
}

// ---------------- node MLP layer 1 (fused): h = relu(leaky((x+agg1)@w1+b1)@w2+b2) ----------------
__global__ __launch_bounds__(128) void n1_kernel(
    const float* __restrict__ x, const float* __restrict__ agg,
    const float* __restrict__ w1, const float* __restrict__ b1,
    const float* __restrict__ w2, const float* __restrict__ b2,
    float* __restrict__ hout)
{
    __shared__ __align__(16) float inA[8][NF];
    __shared__ __align__(16) float bufB[8][HD];
    const int tid = threadIdx.x;
    const float bias1 = b1[tid];
    const float bias2 = b2[tid];
    const int ntiles = NNODES / 8;
    for (int tile = blockIdx.x; tile < ntiles; tile += gridDim.x) {
        const size_t base = (size_t)tile * 8 * NF;
        __syncthreads();
        #pragma unroll
        for (int i = tid; i < 8 * NF; i += 128)
            inA[i >> 5][i & 31] = x[base + i] + agg[base + i];
        __syncthreads();
        float acc[8];
        mv8(&inA[0][0], NF, NF, w1, bias1, tid, acc);
        #pragma unroll
        for (int n = 0; n < 8; ++n) bufB[n][tid] = leakyf(acc[n]);
        __syncthreads();
        mv8(&bufB[0][0], HD, HD, w2, bias2, tid, acc);
        const size_t ob = (size_t)tile * 8 * HD;
        #pragma unroll
        for (int n = 0; n < 8; ++n)
            hout[ob + n * HD + tid] = fmaxf(acc[n], 0.0f);   // relu(leaky(z)) == relu(z)
    }
}

// ---- node layer 2 + pooling + node-score head, all fused (h2 never leaves the CU) ----
__global__ __launch_bounds__(128) void n2_kernel(
    const float* __restrict__ h, const float* __restrict__ agg,
    const float* __restrict__ w1, const float* __restrict__ b1,
    const float* __restrict__ w2, const float* __restrict__ b2,
    const float* __restrict__ nw1, const float* __restrict__ nb1,
    const float* __restrict__ nw2, const float* __restrict__ nb2,
    const float* __restrict__ nw3, const float* __restrict__ nb3,
    float* __restrict__ pooled, float* __restrict__ scores)
{
    __shared__ __align__(16) float bufA[8][HD];
    __shared__ __align__(16) float bufB[8][HD];
    __shared__ float red[2][8];
    const int tid = threadIdx.x;
    const float bias1  = b1[tid],  bias2  = b2[tid];
    const float nbias1 = nb1[tid], nbias2 = nb2[tid];
    const float w3v = nw3[tid];
    const float b3v = nb3[0];
    const int ntiles = NNODES / 8;
    for (int tile = blockIdx.x; tile < ntiles; tile += gridDim.x) {
        const size_t base = (size_t)tile * 8 * HD;
        __syncthreads();                                       // S0
        for (int i = tid; i < 8 * HD; i += 128)
            bufA[i >> 7][i & 127] = h[base + i] + agg[base + i];
        __syncthreads();                                       // S1
        float acc[8];
        mv8(&bufA[0][0], HD, HD, w1, bias1, tid, acc);
        #pragma unroll
        for (int n = 0; n < 8; ++n) bufB[n][tid] = leakyf(acc[n]);
        __syncthreads();                                       // S2
        mv8(&bufB[0][0], HD, HD, w2, bias2, tid, acc);
        float h2[8];
        float psum = 0.0f;
        #pragma unroll
        for (int n = 0; n < 8; ++n) { h2[n] = leakyf(acc[n]); psum += h2[n]; }
        atomicAdd(&pooled[(tile >> 7) * HD + tid], psum);      // graph = (tile*8)/1024
        #pragma unroll
        for (int n = 0; n < 8; ++n) bufA[n][tid] = h2[n];      // bufA reads all done before S2
        __syncthreads();                                       // S3
        mv8(&bufA[0][0], HD, HD, nw1, nbias1, tid, acc);
        #pragma unroll
        for (int n = 0; n < 8; ++n) bufB[n][tid] = leakyf(acc[n]);
        __syncthreads();                                       // S4
        mv8(&bufB[0][0], HD, HD, nw2, nbias2, tid, acc);
        float v[8];
        #pragma unroll
        for (int n = 0; n < 8; ++n) v[n] = leakyf(acc[n]) * w3v;
        #pragma unroll
        for (int off = 32; off >= 1; off >>= 1) {
            #pragma unroll
            for (int n = 0; n < 8; ++n) v[n] += __shfl_xor(v[n], off, 64);
        }
        if ((tid & 63) == 0) {
            const int wv = tid >> 6;
            #pragma unroll
            for (int n = 0; n < 8; ++n) red[wv][n] = v[n];
        }
        __syncthreads();                                       // S5
        if (tid < 8) {
            const int node = tile * 8 + tid;
            const float s = red[0][tid] + red[1][tid] + b3v;
            const float sc = 1.0f / (1.0f + expf(-s));
            scores[(node & 63) * NPER + (node >> 6)] = sc;     // [B, Nper] transpose
        }
    }
}

// ---------------- action head: pooled mean -> MLP -> softmax ----------------
__global__ __launch_bounds__(128) void act_kernel(
    const float* __restrict__ pooled,
    const float* __restrict__ w1, const float* __restrict__ b1,
    const float* __restrict__ w2, const float* __restrict__ b2,
    float* __restrict__ out)
{
    __shared__ __align__(16) float p[HD];
    __shared__ float a1[HD];
    __shared__ float z[NACT];
    __shared__ float red2[2];
    const int g = blockIdx.x;
    const int tid = threadIdx.x;
    p[tid] = pooled[g * HD + tid] * (1.0f / NPER);
    __syncthreads();
    float acc = b1[tid];
    for (int k = 0; k < HD; ++k) acc = fmaf(p[k], w1[k * HD + tid], acc);
    a1[tid] = leakyf(acc);
    __syncthreads();
    if (tid < NACT) {
        float a2 = b2[tid];
        for (int k = 0; k < HD; ++k) a2 = fmaf(a1[k], w2[k * NACT + tid], a2);
        z[tid] = leakyf(a2);
    }
    __syncthreads();
    if (tid == 0) {
        float m = z[0];
        for (int i = 1; i < NACT; ++i) m = fmaxf(m, z[i]);
        red2[0] = m;
    }
    __syncthreads();
    if (tid < NACT) z[tid] = expf(z[tid] - red2[0]);
    __syncthreads();
    if (tid == 0) {
        float s = 0.0f;
        for (int i = 0; i < NACT; ++i) s += z[i];
        red2[1] = s;
    }
    __syncthreads();
    if (tid < NACT) out[g * NACT + tid] = z[tid] / red2[1];
}

extern "C" void kernel_launch(void* const* d_in, const int* in_sizes, int n_in,
                              void* d_out, int out_size, void* d_ws, size_t ws_size,
                              hipStream_t stream)
{
    const float* x    = (const float*)d_in[0];
    const int*   ei   = (const int*)d_in[1];     // int32
    const float* ea   = (const float*)d_in[2];
    const float* e1w  = (const float*)d_in[3];
    const float* e1b  = (const float*)d_in[4];
    const float* c1w1 = (const float*)d_in[5];
    const float* c1b1 = (const float*)d_in[6];
    const float* c1w2 = (const float*)d_in[7];
    const float* c1b2 = (const float*)d_in[8];
    const float* e2w  = (const float*)d_in[9];
    const float* e2b  = (const float*)d_in[10];
    const float* c2w1 = (const float*)d_in[11];
    const float* c2b1 = (const float*)d_in[12];
    const float* c2w2 = (const float*)d_in[13];
    const float* c2b2 = (const float*)d_in[14];
    const float* aw1  = (const float*)d_in[15];
    const float* ab1  = (const float*)d_in[16];
    const float* aw2  = (const float*)d_in[17];
    const float* ab2  = (const float*)d_in[18];
    const float* nw1  = (const float*)d_in[19];
    const float* nb1  = (const float*)d_in[20];
    const float* nw2  = (const float*)d_in[21];
    const float* nb2  = (const float*)d_in[22];
    const float* nw3  = (const float*)d_in[23];
    const float* nb3  = (const float*)d_in[24];

    float* out = (float*)d_out;
    char*  ws  = (char*)d_ws;
    const size_t MB = 1024 * 1024;
    // ws layout (84 MB total):
    // agg1 8MB | h 32MB | agg2 32MB | pooled 32KB | cnt 256KB | fill 256KB |
    // row_start 256KB+4 | sorted_src 4MB | sorted_eidx 4MB
    float* agg1   = (float*)(ws);
    float* h      = (float*)(ws + 8  * MB);
    float* agg2   = (float*)(ws + 40 * MB);
    float* pooled = (float*)(ws + 72 * MB);
    int*   cnt    = (int*)  (ws + 73 * MB);
    int*   fill   = (int*)  (ws + 74 * MB);
    int*   rs     = (int*)  (ws + 75 * MB);
    int*   ssrc   = (int*)  (ws + 76 * MB);
    int*   seidx  = (int*)  (ws + 80 * MB);

    hipMemsetAsync(cnt,    0, NNODES * sizeof(int), stream);
    hipMemsetAsync(fill,   0, NNODES * sizeof(int), stream);
    hipMemsetAsync(pooled, 0, (size_t)NB * HD * sizeof(float), stream);

    // CSR build (dst-sorted edge permutation) — reused by both edge layers
    hist_kernel<<<NEDGES / 256, 256, 0, stream>>>(ei, cnt);
    scan_kernel<<<1, 1024, 0, stream>>>(cnt, rs);
    scatter_kernel<<<NEDGES / 256, 256, 0, stream>>>(ei, rs, fill, ssrc, seidx);

    e1_agg_kernel<<<NNODES / 4, 256, 0, stream>>>(x, rs, ssrc, seidx, ea, e1w, e1b, agg1);
    n1_kernel<<<8192, 128, 0, stream>>>(x, agg1, c1w1, c1b1, c1w2, c1b2, h);
    e2_agg_kernel<<<NNODES / 4, 256, 0, stream>>>(h, rs, ssrc, seidx, ea, e2w, e2b, agg2);
    n2_kernel<<<8192, 128, 0, stream>>>(h, agg2, c2w1, c2b1, c2w2, c2b2,
                                        nw1, nb1, nw2, nb2, nw3, nb3,
                                        pooled, out + NB * NACT);
    act_kernel<<<NB, 128, 0, stream>>>(pooled, aw1, ab1, aw2, ab2, out);
}

// Round 3
// 757.258 us; speedup vs baseline: 3.5301x; 1.3048x over previous
//
#include <hip/hip_runtime.h>
#include <math.h>

#define NNODES 65536
#define NEDGES 1048576
#define NF 32
#define EF 16
#define HD 128
#define NACT 10
#define NB 64
#define NPER 1024

__device__ __forceinline__ float leakyf(float v) { return v > 0.0f ? v : 0.01f * v; }

// ---------------- CSR build: histogram -> scan -> scatter(+ea permute) ----------------
__global__ __launch_bounds__(256) void hist_kernel(const int* __restrict__ ei, int* __restrict__ cnt)
{
    const int i = blockIdx.x * 256 + threadIdx.x;
    if (i < NEDGES) atomicAdd(&cnt[ei[NEDGES + i]], 1);
}

__global__ __launch_bounds__(1024) void scan_kernel(const int* __restrict__ cnt, int* __restrict__ rs)
{
    __shared__ int s[1024];
    const int t = threadIdx.x;
    int loc[64];
    int tot = 0;
    const int4* c4 = (const int4*)(cnt + t * 64);
    #pragma unroll
    for (int j = 0; j < 16; ++j) {
        const int4 v = c4[j];
        loc[4*j+0] = v.x; loc[4*j+1] = v.y; loc[4*j+2] = v.z; loc[4*j+3] = v.w;
        tot += v.x + v.y + v.z + v.w;
    }
    s[t] = tot;
    __syncthreads();
    for (int off = 1; off < 1024; off <<= 1) {
        const int v = (t >= off) ? s[t - off] : 0;
        __syncthreads();
        s[t] += v;
        __syncthreads();
    }
    int run = s[t] - tot;   // exclusive prefix
    #pragma unroll
    for (int j = 0; j < 64; ++j) { rs[t * 64 + j] = run; run += loc[j]; }
    if (t == 0) rs[NNODES] = NEDGES;
}

__global__ __launch_bounds__(256) void scatter_kernel(
    const int* __restrict__ ei, const float* __restrict__ ea,
    const int* __restrict__ rs, int* __restrict__ fill,
    int* __restrict__ ssrc, float* __restrict__ sea)
{
    const int i = blockIdx.x * 256 + threadIdx.x;
    if (i < NEDGES) {
        const int d = ei[NEDGES + i];
        const int pos = rs[d] + atomicAdd(&fill[d], 1);
        ssrc[pos] = ei[i];
        const float4* s4 = (const float4*)ea + (size_t)i * 4;
        float4*       d4 = (float4*)sea + (size_t)pos * 4;
        d4[0] = s4[0]; d4[1] = s4[1]; d4[2] = s4[2]; d4[3] = s4[3];
    }
}

// ---------------- edge layer 1 (gather): agg1[n] = sum relu(x[src] + ea@W + b) ----------------
// One wave per node; f = lane&31, two halves split the edge list; each half unrolled x2.
__global__ __launch_bounds__(256) void e1_agg_kernel(
    const float* __restrict__ x, const int* __restrict__ rs,
    const int* __restrict__ ssrc, const float* __restrict__ sea,
    const float* __restrict__ w, const float* __restrict__ b, float* __restrict__ agg)
{
    const int tid  = threadIdx.x;
    const int lane = tid & 63;
    const int f    = lane & 31;
    const int half = lane >> 5;
    const int node = blockIdx.x * 4 + (tid >> 6);
    float wr[EF];
    #pragma unroll
    for (int k = 0; k < EF; ++k) wr[k] = w[k * NF + f];
    const float bf = b[f];
    const int beg = rs[node], end = rs[node + 1];
    float acc = 0.0f;
    int e = beg + half;
    for (; e + 2 < end; e += 4) {                  // edges e and e+2 in this half-chain
        const int sA = ssrc[e], sB = ssrc[e + 2];
        const float4* pA = (const float4*)sea + (size_t)e * 4;
        const float4* pB = (const float4*)sea + (size_t)(e + 2) * 4;
        const float4 A0 = pA[0], A1 = pA[1], A2 = pA[2], A3 = pA[3];
        const float4 B0 = pB[0], B1 = pB[1], B2 = pB[2], B3 = pB[3];
        const float xA = x[(size_t)sA * NF + f];
        const float xB = x[(size_t)sB * NF + f];
        float evA[EF] = {A0.x,A0.y,A0.z,A0.w, A1.x,A1.y,A1.z,A1.w,
                         A2.x,A2.y,A2.z,A2.w, A3.x,A3.y,A3.z,A3.w};
        float evB[EF] = {B0.x,B0.y,B0.z,B0.w, B1.x,B1.y,B1.z,B1.w,
                         B2.x,B2.y,B2.z,B2.w, B3.x,B3.y,B3.z,B3.w};
        float mA = bf, mB = bf;
        #pragma unroll
        for (int k = 0; k < EF; ++k) {
            mA = fmaf(evA[k], wr[k], mA);
            mB = fmaf(evB[k], wr[k], mB);
        }
        acc += fmaxf(xA + mA, 0.0f) + fmaxf(xB + mB, 0.0f);
    }
    for (; e < end; e += 2) {
        const int sA = ssrc[e];
        const float4* pA = (const float4*)sea + (size_t)e * 4;
        const float4 A0 = pA[0], A1 = pA[1], A2 = pA[2], A3 = pA[3];
        float evA[EF] = {A0.x,A0.y,A0.z,A0.w, A1.x,A1.y,A1.z,A1.w,
                         A2.x,A2.y,A2.z,A2.w, A3.x,A3.y,A3.z,A3.w};
        float mA = bf;
        #pragma unroll
        for (int k = 0; k < EF; ++k) mA = fmaf(evA[k], wr[k], mA);
        acc += fmaxf(x[(size_t)sA * NF + f] + mA, 0.0f);
    }
    acc += __shfl_xor(acc, 32, 64);
    if (half == 0) agg[(size_t)node * NF + f] = acc;
}

// ---------------- edge layer 2 (gather): agg2[n] = sum relu(h[src] + ea@W + b) ----------------
// One wave per node; lane owns features lane and lane+64; edge loop unrolled x2.
__global__ __launch_bounds__(256) void e2_agg_kernel(
    const float* __restrict__ h, const int* __restrict__ rs,
    const int* __restrict__ ssrc, const float* __restrict__ sea,
    const float* __restrict__ w, const float* __restrict__ b, float* __restrict__ agg)
{
    const int tid  = threadIdx.x;
    const int lane = tid & 63;
    const int node = blockIdx.x * 4 + (tid >> 6);
    float wr0[EF], wr1[EF];
    #pragma unroll
    for (int k = 0; k < EF; ++k) {
        wr0[k] = w[k * HD + lane];
        wr1[k] = w[k * HD + lane + 64];
    }
    const float b0 = b[lane], b1 = b[lane + 64];
    const int beg = rs[node], end = rs[node + 1];
    float acc0 = 0.0f, acc1 = 0.0f;
    int e = beg;
    for (; e + 2 <= end; e += 2) {
        const int sA = ssrc[e], sB = ssrc[e + 1];
        const float4* pA = (const float4*)sea + (size_t)e * 4;
        const float4 A0 = pA[0], A1 = pA[1], A2 = pA[2], A3 = pA[3];
        const float4 B0 = pA[4], B1 = pA[5], B2 = pA[6], B3 = pA[7];
        const float hA0 = h[(size_t)sA * HD + lane];
        const float hA1 = h[(size_t)sA * HD + lane + 64];
        const float hB0 = h[(size_t)sB * HD + lane];
        const float hB1 = h[(size_t)sB * HD + lane + 64];
        float evA[EF] = {A0.x,A0.y,A0.z,A0.w, A1.x,A1.y,A1.z,A1.w,
                         A2.x,A2.y,A2.z,A2.w, A3.x,A3.y,A3.z,A3.w};
        float evB[EF] = {B0.x,B0.y,B0.z,B0.w, B1.x,B1.y,B1.z,B1.w,
                         B2.x,B2.y,B2.z,B2.w, B3.x,B3.y,B3.z,B3.w};
        float mA0 = b0, mA1 = b1, mB0 = b0, mB1 = b1;
        #pragma unroll
        for (int k = 0; k < EF; ++k) {
            mA0 = fmaf(evA[k], wr0[k], mA0);
            mA1 = fmaf(evA[k], wr1[k], mA1);
            mB0 = fmaf(evB[k], wr0[k], mB0);
            mB1 = fmaf(evB[k], wr1[k], mB1);
        }
        acc0 += fmaxf(hA0 + mA0, 0.0f) + fmaxf(hB0 + mB0, 0.0f);
        acc1 += fmaxf(hA1 + mA1, 0.0f) + fmaxf(hB1 + mB1, 0.0f);
    }
    if (e < end) {
        const int sA = ssrc[e];
        const float4* pA = (const float4*)sea + (size_t)e * 4;
        const float4 A0 = pA[0], A1 = pA[1], A2 = pA[2], A3 = pA[3];
        float evA[EF] = {A0.x,A0.y,A0.z,A0.w, A1.x,A1.y,A1.z,A1.w,
                         A2.x,A2.y,A2.z,A2.w, A3.x,A3.y,A3.z,A3.w};
        float mA0 = b0, mA1 = b1;
        #pragma unroll
        for (int k = 0; k < EF; ++k) {
            mA0 = fmaf(evA[k], wr0[k], mA0);
            mA1 = fmaf(evA[k], wr1[k], mA1);
        }
        acc0 += fmaxf(h[(size_t)sA * HD + lane]      + mA0, 0.0f);
        acc1 += fmaxf(h[(size_t)sA * HD + lane + 64] + mA1, 0.0f);
    }
    agg[(size_t)node * HD + lane]      = acc0;
    agg[(size_t)node * HD + lane + 64] = acc1;
}

// 8-node matvec, 2 output features per lane (f, f+64): each input float4 feeds 8 FMAs.
__device__ __forceinline__ void mv8x2(const float* __restrict__ sIn, int ld, int K,
                                      const float* __restrict__ w, float bias0, float bias1,
                                      int f, float* __restrict__ acc0, float* __restrict__ acc1)
{
    #pragma unroll
    for (int n = 0; n < 8; ++n) { acc0[n] = bias0; acc1[n] = bias1; }
    for (int k = 0; k < K; k += 4) {
        const float w00 = w[(k + 0) * HD + f],      w01 = w[(k + 1) * HD + f];
        const float w02 = w[(k + 2) * HD + f],      w03 = w[(k + 3) * HD + f];
        const float w10 = w[(k + 0) * HD + f + 64], w11 = w[(k + 1) * HD + f + 64];
        const float w12 = w[(k + 2) * HD + f + 64], w13 = w[(k + 3) * HD + f + 64];
        #pragma unroll
        for (int n = 0; n < 8; ++n) {
            const float4 iv = *(const float4*)&sIn[n * ld + k];
            acc0[n] = fmaf(iv.w, w03, fmaf(iv.z, w02, fmaf(iv.y, w01, fmaf(iv.x, w00, acc0[n]))));
            acc1[n] = fmaf(iv.w, w13, fmaf(iv.z, w12, fmaf(iv.y, w11, fmaf(iv.x, w10, acc1[n]))));
        }
    }
}

// ---------------- node MLP layer 1 (fused): h = relu(leaky((x+agg1)@w1+b1)@w2+b2) ----------------
// 64-thread blocks (1 wave), 8 nodes per block.
__global__ __launch_bounds__(64) void n1_kernel(
    const float* __restrict__ x, const float* __restrict__ agg,
    const float* __restrict__ w1, const float* __restrict__ b1,
    const float* __restrict__ w2, const float* __restrict__ b2,
    float* __restrict__ hout)
{
    __shared__ __align__(16) float inA[8 * NF];
    __shared__ __align__(16) float bufB[8 * HD];
    const int f = threadIdx.x;
    const int tile = blockIdx.x;
    const float bias10 = b1[f], bias11 = b1[f + 64];
    const float bias20 = b2[f], bias21 = b2[f + 64];
    const size_t base = (size_t)tile * 8 * NF;
    {
        const float4 xv = *(const float4*)&x[base + f * 4];
        const float4 av = *(const float4*)&agg[base + f * 4];
        *(float4*)&inA[f * 4] = make_float4(xv.x + av.x, xv.y + av.y, xv.z + av.z, xv.w + av.w);
    }
    __syncthreads();
    float acc0[8], acc1[8];
    mv8x2(inA, NF, NF, w1, bias10, bias11, f, acc0, acc1);
    #pragma unroll
    for (int n = 0; n < 8; ++n) {
        bufB[n * HD + f]      = leakyf(acc0[n]);
        bufB[n * HD + f + 64] = leakyf(acc1[n]);
    }
    __syncthreads();
    mv8x2(bufB, HD, HD, w2, bias20, bias21, f, acc0, acc1);
    const size_t ob = (size_t)tile * 8 * HD;
    #pragma unroll
    for (int n = 0; n < 8; ++n) {
        hout[ob + n * HD + f]      = fmaxf(acc0[n], 0.0f);   // relu(leaky(z)) == relu(z)
        hout[ob + n * HD + f + 64] = fmaxf(acc1[n], 0.0f);
    }
}

// ---- node layer 2 + pooling + node-score head, all fused (h2 never leaves the CU) ----
__global__ __launch_bounds__(64) void n2_kernel(
    const float* __restrict__ h, const float* __restrict__ agg,
    const float* __restrict__ w1, const float* __restrict__ b1,
    const float* __restrict__ w2, const float* __restrict__ b2,
    const float* __restrict__ nw1, const float* __restrict__ nb1,
    const float* __restrict__ nw2, const float* __restrict__ nb2,
    const float* __restrict__ nw3, const float* __restrict__ nb3,
    float* __restrict__ pooled, float* __restrict__ scores)
{
    __shared__ __align__(16) float bufA[8 * HD];
    __shared__ __align__(16) float bufB[8 * HD];
    const int f = threadIdx.x;
    const int tile = blockIdx.x;
    const float bias10  = b1[f],  bias11  = b1[f + 64];
    const float bias20  = b2[f],  bias21  = b2[f + 64];
    const float nbias10 = nb1[f], nbias11 = nb1[f + 64];
    const float nbias20 = nb2[f], nbias21 = nb2[f + 64];
    const float w3v0 = nw3[f], w3v1 = nw3[f + 64];
    const float b3v = nb3[0];
    const size_t base = (size_t)tile * 8 * HD;
    #pragma unroll
    for (int j = 0; j < 4; ++j) {
        const int i = (f + j * 64) * 4;
        const float4 hv = *(const float4*)&h[base + i];
        const float4 av = *(const float4*)&agg[base + i];
        *(float4*)&bufA[i] = make_float4(hv.x + av.x, hv.y + av.y, hv.z + av.z, hv.w + av.w);
    }
    __syncthreads();
    float acc0[8], acc1[8];
    mv8x2(bufA, HD, HD, w1, bias10, bias11, f, acc0, acc1);
    #pragma unroll
    for (int n = 0; n < 8; ++n) {
        bufB[n * HD + f]      = leakyf(acc0[n]);
        bufB[n * HD + f + 64] = leakyf(acc1[n]);
    }
    __syncthreads();
    mv8x2(bufB, HD, HD, w2, bias20, bias21, f, acc0, acc1);
    float psum0 = 0.0f, psum1 = 0.0f;
    #pragma unroll
    for (int n = 0; n < 8; ++n) {
        acc0[n] = leakyf(acc0[n]);
        acc1[n] = leakyf(acc1[n]);
        psum0 += acc0[n];
        psum1 += acc1[n];
    }
    const int g = tile >> 7;                         // graph id (1024 nodes = 128 tiles each)
    atomicAdd(&pooled[g * HD + f],      psum0);
    atomicAdd(&pooled[g * HD + f + 64], psum1);
    __syncthreads();
    #pragma unroll
    for (int n = 0; n < 8; ++n) {
        bufA[n * HD + f]      = acc0[n];
        bufA[n * HD + f + 64] = acc1[n];
    }
    __syncthreads();
    mv8x2(bufA, HD, HD, nw1, nbias10, nbias11, f, acc0, acc1);
    #pragma unroll
    for (int n = 0; n < 8; ++n) {
        bufB[n * HD + f]      = leakyf(acc0[n]);
        bufB[n * HD + f + 64] = leakyf(acc1[n]);
    }
    __syncthreads();
    mv8x2(bufB, HD, HD, nw2, nbias20, nbias21, f, acc0, acc1);
    float v[8];
    #pragma unroll
    for (int n = 0; n < 8; ++n)
        v[n] = leakyf(acc0[n]) * w3v0 + leakyf(acc1[n]) * w3v1;
    #pragma unroll
    for (int off = 32; off >= 1; off >>= 1) {
        #pragma unroll
        for (int n = 0; n < 8; ++n) v[n] += __shfl_xor(v[n], off, 64);
    }
    if (f < 8) {
        const int node = tile * 8 + f;
        const float s = v[f] + b3v;                  // every lane holds full sums post-butterfly
        const float sc = 1.0f / (1.0f + expf(-s));
        scores[(node & 63) * NPER + (node >> 6)] = sc;   // [B, Nper] transpose
    }
}

// ---------------- action head: pooled mean -> MLP -> softmax ----------------
__global__ __launch_bounds__(128) void act_kernel(
    const float* __restrict__ pooled,
    const float* __restrict__ w1, const float* __restrict__ b1,
    const float* __restrict__ w2, const float* __restrict__ b2,
    float* __restrict__ out)
{
    __shared__ __align__(16) float p[HD];
    __shared__ float a1[HD];
    __shared__ float z[NACT];
    __shared__ float red2[2];
    const int g = blockIdx.x;
    const int tid = threadIdx.x;
    p[tid] = pooled[g * HD + tid] * (1.0f / NPER);
    __syncthreads();
    float acc = b1[tid];
    for (int k = 0; k < HD; ++k) acc = fmaf(p[k], w1[k * HD + tid], acc);
    a1[tid] = leakyf(acc);
    __syncthreads();
    if (tid < NACT) {
        float a2 = b2[tid];
        for (int k = 0; k < HD; ++k) a2 = fmaf(a1[k], w2[k * NACT + tid], a2);
        z[tid] = leakyf(a2);
    }
    __syncthreads();
    if (tid == 0) {
        float m = z[0];
        for (int i = 1; i < NACT; ++i) m = fmaxf(m, z[i]);
        red2[0] = m;
    }
    __syncthreads();
    if (tid < NACT) z[tid] = expf(z[tid] - red2[0]);
    __syncthreads();
    if (tid == 0) {
        float s = 0.0f;
        for (int i = 0; i < NACT; ++i) s += z[i];
        red2[1] = s;
    }
    __syncthreads();
    if (tid < NACT) out[g * NACT + tid] = z[tid] / red2[1];
}

extern "C" void kernel_launch(void* const* d_in, const int* in_sizes, int n_in,
                              void* d_out, int out_size, void* d_ws, size_t ws_size,
                              hipStream_t stream)
{
    const float* x    = (const float*)d_in[0];
    const int*   ei   = (const int*)d_in[1];     // int32
    const float* ea   = (const float*)d_in[2];
    const float* e1w  = (const float*)d_in[3];
    const float* e1b  = (const float*)d_in[4];
    const float* c1w1 = (const float*)d_in[5];
    const float* c1b1 = (const float*)d_in[6];
    const float* c1w2 = (const float*)d_in[7];
    const float* c1b2 = (const float*)d_in[8];
    const float* e2w  = (const float*)d_in[9];
    const float* e2b  = (const float*)d_in[10];
    const float* c2w1 = (const float*)d_in[11];
    const float* c2b1 = (const float*)d_in[12];
    const float* c2w2 = (const float*)d_in[13];
    const float* c2b2 = (const float*)d_in[14];
    const float* aw1  = (const float*)d_in[15];
    const float* ab1  = (const float*)d_in[16];
    const float* aw2  = (const float*)d_in[17];
    const float* ab2  = (const float*)d_in[18];
    const float* nw1  = (const float*)d_in[19];
    const float* nb1  = (const float*)d_in[20];
    const float* nw2  = (const float*)d_in[21];
    const float* nb2  = (const float*)d_in[22];
    const float* nw3  = (const float*)d_in[23];
    const float* nb3  = (const float*)d_in[24];

    float* out = (float*)d_out;
    char*  ws  = (char*)d_ws;
    const size_t MB = 1024 * 1024;
    // ws layout (~144 MB): h 32 | agg2 32 | sea 64 | agg1 8 | pooled | cnt | fill | rs | ssrc 4
    float* h      = (float*)(ws);
    float* agg2   = (float*)(ws + 32  * MB);
    float* sea    = (float*)(ws + 64  * MB);
    float* agg1   = (float*)(ws + 128 * MB);
    float* pooled = (float*)(ws + 136 * MB);
    int*   cnt    = (int*)  (ws + 137 * MB);
    int*   fill   = (int*)  (ws + 138 * MB);
    int*   rs     = (int*)  (ws + 139 * MB);
    int*   ssrc   = (int*)  (ws + 140 * MB);

    hipMemsetAsync(cnt,    0, NNODES * sizeof(int), stream);
    hipMemsetAsync(fill,   0, NNODES * sizeof(int), stream);
    hipMemsetAsync(pooled, 0, (size_t)NB * HD * sizeof(float), stream);

    // CSR build (dst-sorted edge permutation, edge_attr physically permuted)
    hist_kernel<<<NEDGES / 256, 256, 0, stream>>>(ei, cnt);
    scan_kernel<<<1, 1024, 0, stream>>>(cnt, rs);
    scatter_kernel<<<NEDGES / 256, 256, 0, stream>>>(ei, ea, rs, fill, ssrc, sea);

    e1_agg_kernel<<<NNODES / 4, 256, 0, stream>>>(x, rs, ssrc, sea, e1w, e1b, agg1);
    n1_kernel<<<NNODES / 8, 64, 0, stream>>>(x, agg1, c1w1, c1b1, c1w2, c1b2, h);
    e2_agg_kernel<<<NNODES / 4, 256, 0, stream>>>(h, rs, ssrc, sea, e2w, e2b, agg2);
    n2_kernel<<<NNODES / 8, 64, 0, stream>>>(h, agg2, c2w1, c2b1, c2w2, c2b2,
                                             nw1, nb1, nw2, nb2, nw3, nb3,
                                             pooled, out + NB * NACT);
    act_kernel<<<NB, 128, 0, stream>>>(pooled, aw1, ab1, aw2, ab2, out);
}